// Round 8
// baseline (157244.336 us; speedup 1.0000x reference)
//
#include <hip/hip_runtime.h>

typedef unsigned short u16;
typedef __attribute__((ext_vector_type(4))) float f32x4;
typedef __attribute__((ext_vector_type(8))) short short8;

#define NUM_T 256
#define BATCH 1024
#define DIM 64
#define HID 768
#define PHID 512
#define PREP 10
#define GIN 640            // DIM*PREP
#define COVSZ 32
#define COVH 128
#define DT_ 0.05f
#define VEPS 1e-6f
#define NTH 512
#define NWAVE 8
#define NWG 64

// LDS row strides (elements)
#define LHF 772
#define LHB 776
#define LPH 520
#define LPF 132
#define LPB 136
#define LGI 648

struct Params {
  const float *X, *M; const int *obs; const float *cov;
  const float *bxz, *bxn, *bp1, *bp2, *bc1, *bc2, *bih, *bhh, *wprep, *bprep;
  const float *Wc1, *Wc2;
  const u16 *Wxz, *Wxn, *Whz, *Whn, *Wp1, *Wp2, *Wih, *Whh;
  float *out_h; float *partials;
};

__device__ __forceinline__ u16 f2bf(float f){
  unsigned u = __builtin_bit_cast(unsigned, f);
  u = (u + 0x7FFFu + ((u >> 16) & 1u)) >> 16;
  return (u16)u;
}
__device__ __forceinline__ float bf2f(u16 h){
  unsigned u = ((unsigned)h) << 16;
  return __builtin_bit_cast(float, u);
}
__device__ __forceinline__ float sigm(float x){ return 1.0f/(1.0f + __expf(-x)); }
__device__ __forceinline__ float tanh_f(float x){
  float t = __expf(-2.0f*fabsf(x));
  float r = (1.0f - t)/(1.0f + t);
  return x >= 0.0f ? r : -r;
}

struct Smem {
  float h_f[16*LHF];     // fp32 master h
  u16   h_b[16*LHB];     // bf16 copy (MFMA A operand)
  u16   ph1[16*LPH];
  float p_f[16*LPF];     // fp32 p for NLL
  u16   p_b[16*LPB];     // bf16 p for ODE GEMMs
  union U {
    struct ZN { u16 z_b[16*LHB]; u16 zh_b[16*LHB]; } zn;
    u16 gi_b[16*LGI];
  } u;
  int om[2][16];
  float red[NWAVE];
};

// Weights pre-swizzled fragment-major: W2[((t*NK + k)*64 + lane)*8 + e]
//   = W[t*16 + (lane&15)][k*32 + (lane>>4)*8 + e]
// One wave k-step load = contiguous 1KB per tile. NO explicit prefetch
// rotation: direct indexed loads, compiler schedules the pipeline (the
// explicit depth-D rotation in r3 serialized it; the ring DMA in r4-r7
// corrupted it). This is the r2/r3-verified data path, simplified.
template<int K, int NT, int TS>
__device__ __forceinline__ void dotF(const u16* __restrict__ A, int lda,
    const u16* __restrict__ W2, int t0, f32x4* acc, int c, int g, int lane)
{
  constexpr int NK = K/32;
  const u16* a = A + c*lda + g*8;
  const short8* wp[NT];
  #pragma unroll
  for (int j = 0; j < NT; ++j)
    wp[j] = (const short8*)W2 + ((size_t)(t0 + TS*j)*NK)*64 + lane;
  #pragma unroll
  for (int k = 0; k < NK; ++k){
    short8 av = *(const short8*)(a + 32*k);
    #pragma unroll
    for (int j = 0; j < NT; ++j)
      acc[j] = __builtin_amdgcn_mfma_f32_16x16x32_bf16(av, wp[j][64*k], acc[j], 0, 0, 0);
  }
}

__global__ __launch_bounds__(NTH, 1) void nnfo_main(Params pr)
{
  __shared__ Smem sm;
  const int tid  = threadIdx.x;
  const int lane = tid & 63;
  const int w    = tid >> 6;          // wave 0..7
  const int c = lane & 15;            // output col / A row
  const int g = lane >> 4;            // k-group; output rows g*4+i
  const int wg = blockIdx.x;
  const int row0 = wg * 16;

  float loss = 0.0f;

  // ---- prologue: h0 = tanh(relu(cov@Wc1^T + bc1)@Wc2^T + bc2) ----
  for (int it = tid; it < 16*COVH; it += NTH){
    int r = it >> 7, j = it & 127;
    float acc = pr.bc1[j];
    const float* cv = pr.cov + (size_t)(row0 + r)*COVSZ;
    const float* wv = pr.Wc1 + (size_t)j*COVSZ;
    for (int k = 0; k < COVSZ; ++k) acc += cv[k]*wv[k];
    sm.p_f[r*LPF + j] = fmaxf(acc, 0.0f);
  }
  __syncthreads();
  for (int it = tid; it < 16*HID; it += NTH){
    int r = it / HID, j = it - r*HID;
    float acc = pr.bc2[j];
    const float* wv = pr.Wc2 + (size_t)j*COVH;
    for (int k = 0; k < COVH; ++k) acc += sm.p_f[r*LPF + k]*wv[k];
    float h = tanh_f(acc);
    sm.h_f[r*LHF + j] = h;
    sm.h_b[r*LHB + j] = f2bf(h);
  }
  __syncthreads();

  // p_model part 1: ph1 = relu(h@Wp1^T + bp1)   (N=512 -> 32 tiles, NT=4)
  auto pm1 = [&]() {
    f32x4 acc[4] = {};
    dotF<HID, 4, 8>(sm.h_b, LHB, pr.Wp1, w, acc, c, g, lane);
    #pragma unroll
    for (int j = 0; j < 4; ++j){
      int n = (w + 8*j)*16 + c;
      float b = pr.bp1[n];
      #pragma unroll
      for (int i = 0; i < 4; ++i)
        sm.ph1[(g*4 + i)*LPH + n] = f2bf(fmaxf(acc[j][i] + b, 0.0f));
    }
  };
  // p_model part 2 (N=128 -> 8 tiles, NT=1). write_pb: also store bf16 p.
  auto pm2 = [&](bool write_pb) {
    f32x4 acc[1] = {};
    dotF<PHID, 1, 8>(sm.ph1, LPH, pr.Wp2, w, acc, c, g, lane);
    int n = w*16 + c;
    float b = pr.bp2[n];
    #pragma unroll
    for (int i = 0; i < 4; ++i){
      float v = acc[0][i] + b;
      sm.p_f[(g*4 + i)*LPF + n] = v;
      if (write_pb) sm.p_b[(g*4 + i)*LPB + n] = f2bf(v);
    }
  };

  // initial p = p_model(h0) (pre-ODE p for step 0)
  pm1();
  __syncthreads();
  pm2(true);
  __syncthreads();

  float Xs[2], Ms[2];   // stashed X and M*om between nll_pre and nll_post

  #pragma unroll 1
  for (int t = 0; t < NUM_T; ++t){
    if (tid < 16) sm.om[t & 1][tid] = pr.obs[(size_t)t*BATCH + row0 + tid];

    // ---- A1: z = sigmoid(p@Wxz + bxz + h@Whz); accn = p@Wxn (partial) ----
    {
      f32x4 accz[6] = {}, accn[6] = {};
      dotF<128, 6, 8>(sm.p_b, LPB, pr.Wxz, w, accz, c, g, lane);
      dotF<HID, 6, 8>(sm.h_b, LHB, pr.Whz, w, accz, c, g, lane);
      dotF<128, 6, 8>(sm.p_b, LPB, pr.Wxn, w, accn, c, g, lane);
      #pragma unroll
      for (int j = 0; j < 6; ++j){
        int n = (w + 8*j)*16 + c;
        float b = pr.bxz[n];
        #pragma unroll
        for (int i = 0; i < 4; ++i){
          int r = g*4 + i;
          float z = sigm(accz[j][i] + b);
          float h = sm.h_f[r*LHF + n];
          sm.u.zn.z_b [r*LHB + n] = f2bf(z);
          sm.u.zn.zh_b[r*LHB + n] = f2bf(z*h);
        }
      }
      __syncthreads();

      // ---- A2: n = tanh(accn + bxn + (z*h)@Whn); h += dt*(1-z)*(n-h) ----
      dotF<HID, 6, 8>(sm.u.zn.zh_b, LHB, pr.Whn, w, accn, c, g, lane);
      #pragma unroll
      for (int j = 0; j < 6; ++j){
        int n = (w + 8*j)*16 + c;
        float b = pr.bxn[n];
        #pragma unroll
        for (int i = 0; i < 4; ++i){
          int r = g*4 + i;
          float nv = tanh_f(accn[j][i] + b);
          float z  = bf2f(sm.u.zn.z_b[r*LHB + n]);
          float h  = sm.h_f[r*LHF + n];
          h = h + DT_*(1.0f - z)*(nv - h);
          sm.h_f[r*LHF + n] = h;
          sm.h_b[r*LHB + n] = f2bf(h);
        }
      }
    }
    __syncthreads();

    // ---- B,C: p2 = p_model(h_ode) -> fp32 only ----
    pm1();
    __syncthreads();
    pm2(false);
    __syncthreads();

    // ---- D: nll_pre + build gi (stash X, M*om) ----
    #pragma unroll
    for (int q = 0; q < 2; ++q){
      int it = tid + q*NTH;
      int r = it >> 6, d = it & 63;
      size_t xoff = ((size_t)t*BATCH + row0 + r)*DIM + d;
      float Xv = pr.X[xoff];
      float om = sm.om[t & 1][r] ? 1.0f : 0.0f;
      float Mv = pr.M[xoff] * om;
      Xs[q] = Xv; Ms[q] = Mv;
      float mean = sm.p_f[r*LPF + d];
      float var  = sm.p_f[r*LPF + 64 + d];
      float av   = fabsf(var) + VEPS;
      float inv  = rsqrtf(av);
      float errv = (Xv - mean)*inv;
      loss += 0.5f*(errv*errv + __logf(av))*Mv;
      #pragma unroll
      for (int p = 0; p < PREP; ++p){
        float s = pr.bprep[d*PREP + p]
                + Xv  * pr.wprep[(d*4 + 0)*PREP + p]
                + mean* pr.wprep[(d*4 + 1)*PREP + p]
                + av  * pr.wprep[(d*4 + 2)*PREP + p]
                + errv* pr.wprep[(d*4 + 3)*PREP + p];
        sm.u.gi_b[r*LGI + d*PREP + p] = f2bf(fmaxf(s, 0.0f)*Mv);
      }
    }
    __syncthreads();

    // ---- E: GRUCell jump ----
    {
      float hn_buf[6][4];
      #pragma unroll
      for (int j = 0; j < 6; ++j){
        int tt = w + 8*j;               // col-tile 0..47
        int n = tt*16 + c;
        f32x4 ai[3] = {};               // r,z,n gates from gi@Wih (TS=48 hops gates)
        dotF<GIN, 3, 48>(sm.u.gi_b, LGI, pr.Wih, tt, ai, c, g, lane);
        f32x4 ah[3] = {};               // gates from h@Whh
        dotF<HID, 3, 48>(sm.h_b, LHB, pr.Whh, tt, ah, c, g, lane);
        #pragma unroll
        for (int i = 0; i < 4; ++i){
          int r = g*4 + i;
          float ir = ai[0][i] + pr.bih[n];
          float iz = ai[1][i] + pr.bih[HID + n];
          float in = ai[2][i] + pr.bih[2*HID + n];
          float hr = ah[0][i] + pr.bhh[n];
          float hz = ah[1][i] + pr.bhh[HID + n];
          float hn = ah[2][i] + pr.bhh[2*HID + n];
          float rr  = sigm(ir + hr);
          float zz  = sigm(iz + hz);
          float nn  = tanh_f(in + rr*hn);
          float ho  = sm.h_f[r*LHF + n];
          hn_buf[j][i] = (1.0f - zz)*nn + zz*ho;
        }
      }
      __syncthreads();   // all reads of h_b/h_f done before conditional overwrite
      #pragma unroll
      for (int j = 0; j < 6; ++j){
        int n = (w + 8*j)*16 + c;
        #pragma unroll
        for (int i = 0; i < 4; ++i){
          int r = g*4 + i;
          if (sm.om[t & 1][r]){
            float v = hn_buf[j][i];
            sm.h_f[r*LHF + n] = v;
            sm.h_b[r*LHB + n] = f2bf(v);
          }
        }
      }
    }
    __syncthreads();

    // ---- F,G: p3 = p_model(h_jump) -> fp32 + bf16 (next step's pre-ODE p) ----
    pm1();
    __syncthreads();
    pm2(true);
    __syncthreads();

    // ---- H: nll_post (reuses stashed X, M*om) ----
    #pragma unroll
    for (int q = 0; q < 2; ++q){
      int it = tid + q*NTH;
      int r = it >> 6, d = it & 63;
      float mean = sm.p_f[r*LPF + d];
      float var  = sm.p_f[r*LPF + 64 + d];
      float av   = fabsf(var) + VEPS;
      float inv  = rsqrtf(av);
      float errv = (Xs[q] - mean)*inv;
      loss += 0.5f*(errv*errv + __logf(av))*Ms[q];   // MIXING = 1
    }
  }

  __syncthreads();
  // ---- write h rows (fp32) ----
  for (int it = tid; it < 16*HID; it += NTH){
    int r = it / HID, j = it - r*HID;
    pr.out_h[(size_t)(row0 + r)*HID + j] = sm.h_f[r*LHF + j];
  }
  // ---- loss reduce ----
  #pragma unroll
  for (int off = 32; off >= 1; off >>= 1) loss += __shfl_down(loss, off);
  if (lane == 0) sm.red[w] = loss;
  __syncthreads();
  if (tid == 0){
    float s = 0.0f;
    for (int i = 0; i < NWAVE; ++i) s += sm.red[i];
    pr.partials[wg] = s;
  }
}

// Convert + swizzle W (N x K, f32 row-major) -> fragment-major bf16:
// dst[((t*ks + k)*64 + lane)*8 + e] = W[t*16 + (lane&15)][k*32 + (lane>>4)*8 + e]
__global__ void k_swz(const float* __restrict__ s, u16* __restrict__ d, int N, int K){
  int i = blockIdx.x*blockDim.x + threadIdx.x;
  if (i >= N*K) return;
  int e    = i & 7;
  int lane = (i >> 3) & 63;
  int rest = i >> 9;             // t*ks + k
  int ks = K >> 5;
  int k = rest % ks, t = rest / ks;
  int cc = lane & 15, gg = lane >> 4;
  d[i] = f2bf(s[(size_t)(t*16 + cc)*K + (k*32 + gg*8 + e)]);
}

__global__ void k_final(const float* __restrict__ partials, float* __restrict__ out_loss){
  float v = partials[threadIdx.x];
  #pragma unroll
  for (int off = 32; off >= 1; off >>= 1) v += __shfl_down(v, off);
  if (threadIdx.x == 0) out_loss[0] = v;
}

extern "C" void kernel_launch(void* const* d_in, const int* in_sizes, int n_in,
                              void* d_out, int out_size, void* d_ws, size_t ws_size,
                              hipStream_t stream)
{
  const float* X   = (const float*)d_in[0];
  const float* M   = (const float*)d_in[1];
  const int*   obs = (const int*)  d_in[2];
  const float* cov = (const float*)d_in[3];
  const float* Wxz = (const float*)d_in[4];
  const float* bxz = (const float*)d_in[5];
  const float* Wxn = (const float*)d_in[6];
  const float* bxn = (const float*)d_in[7];
  const float* Whz = (const float*)d_in[8];
  const float* Whn = (const float*)d_in[9];
  const float* Wp1 = (const float*)d_in[10];
  const float* bp1 = (const float*)d_in[11];
  const float* Wp2 = (const float*)d_in[12];
  const float* bp2 = (const float*)d_in[13];
  const float* Wc1 = (const float*)d_in[14];
  const float* bc1 = (const float*)d_in[15];
  const float* Wc2 = (const float*)d_in[16];
  const float* bc2 = (const float*)d_in[17];
  const float* Wih = (const float*)d_in[18];
  const float* Whh = (const float*)d_in[19];
  const float* bih = (const float*)d_in[20];
  const float* bhh = (const float*)d_in[21];
  const float* wprep = (const float*)d_in[22];
  const float* bprep = (const float*)d_in[23];

  u16* w = (u16*)d_ws;
  u16* wXZ = w + 0;         // 768*128
  u16* wXN = w + 98304;     // 768*128
  u16* wHZ = w + 196608;    // 768*768
  u16* wHN = w + 786432;    // 768*768
  u16* wP1 = w + 1376256;   // 512*768
  u16* wP2 = w + 1769472;   // 128*512
  u16* wIH = w + 1835008;   // 2304*640
  u16* wHH = w + 3309568;   // 2304*768
  float* partials = (float*)((char*)d_ws + 10158080);

  struct CV { const float* s; u16* d; int N; int K; } cvs[8] = {
    {Wxz, wXZ, 768, 128}, {Wxn, wXN, 768, 128}, {Whz, wHZ, 768, 768}, {Whn, wHN, 768, 768},
    {Wp1, wP1, 512, 768}, {Wp2, wP2, 128, 512}, {Wih, wIH, 2304, 640}, {Whh, wHH, 2304, 768},
  };
  for (int i = 0; i < 8; ++i){
    int n = cvs[i].N * cvs[i].K;
    k_swz<<<(n + 255)/256, 256, 0, stream>>>(cvs[i].s, cvs[i].d, cvs[i].N, cvs[i].K);
  }

  Params pr { X, M, obs, cov, bxz, bxn, bp1, bp2, bc1, bc2, bih, bhh, wprep, bprep,
              Wc1, Wc2, wXZ, wXN, wHZ, wHN, wP1, wP2, wIH, wHH,
              (float*)d_out, partials };
  nnfo_main<<<NWG, NTH, 0, stream>>>(pr);
  k_final<<<1, 64, 0, stream>>>(partials, (float*)d_out + (size_t)BATCH*HID);
}

// Round 9
// 63545.837 us; speedup vs baseline: 2.4745x; 2.4745x over previous
//
#include <hip/hip_runtime.h>

typedef unsigned short u16;
typedef __attribute__((ext_vector_type(4))) float f32x4;
typedef __attribute__((ext_vector_type(8))) short short8;

#define NUM_T 256
#define BATCH 1024
#define DIM 64
#define HID 768
#define PHID 512
#define PREP 10
#define GIN 640            // DIM*PREP
#define COVSZ 32
#define COVH 128
#define DT_ 0.05f
#define VEPS 1e-6f
#define NTH 512
#define NWAVE 8
#define NWG 64

// LDS row strides (elements)
#define LHB 776
#define LPH 520
#define LPF 132
#define LPB 136
#define LZH 776
#define LGI 648
#define PANEL (48*512)      // u16 per panel buffer (48 tiles x 1KB)

struct Params {
  const float *X, *M; const int *obs; const float *cov;
  const float *bxz, *bxn, *bp1, *bp2, *bc1, *bc2, *bih, *bhh, *wprep, *bprep;
  const float *Wc1, *Wc2;
  const u16 *Wxz, *Wxn, *Whz, *Whn, *Wp1, *Wp2, *Wih, *Whh;
  float *out_h; float *partials;
};

__device__ __forceinline__ u16 f2bf(float f){
  unsigned u = __builtin_bit_cast(unsigned, f);
  u = (u + 0x7FFFu + ((u >> 16) & 1u)) >> 16;
  return (u16)u;
}
__device__ __forceinline__ float bf2f(u16 h){
  unsigned u = ((unsigned)h) << 16;
  return __builtin_bit_cast(float, u);
}
__device__ __forceinline__ float sigm(float x){ return 1.0f/(1.0f + __expf(-x)); }
__device__ __forceinline__ float tanh_f(float x){
  float t = __expf(-2.0f*fabsf(x));
  float r = (1.0f - t)/(1.0f + t);
  return x >= 0.0f ? r : -r;
}

struct Smem {
  u16   panel[2][PANEL];         // double-buffered weight panels   98304B
  u16   h_b[16*LHB];             // bf16 h (MFMA A operand)         24832B
  float p_f[16*LPF];             // fp32 p for NLL                   8448B
  u16   p_b[16*LPB];             // bf16 p for ODE GEMMs             4352B
  union {                        // phase-disjoint                  24832B
    u16 zh[16*LZH];              //  A1->A2
    u16 gi[16*LGI];              //  D->E
    u16 ph1[16*LPH];             //  pm1->pm2
  } u;
  int om[2][16];
  float red[NWAVE];
};                                // total 160928B <= 160KiB

// Cooperative panel GEMM. Weights pre-swizzled fragment-major:
//   W2[((tile*NKC + kk)*64 + lane)*8 + e] = W[tile*16+(lane&15)][kk*32+(lane>>4)*8+e]
// Per k-chunk, the whole WG stages the 8*NT-tile panel (wave w stages chunks
// {w+8jj}) global->reg->LDS, double-buffered, one barrier per chunk. T14
// ordering: issue loads(kk+1) early, MFMA chunk kk from LDS, ds_write late.
// Values and per-accumulator MFMA k-order identical to the verified r1/r8
// path -> bit-exact.
template<int NKC, int NT>
__device__ __forceinline__ void panelGemm(const u16* __restrict__ A, int lda,
    const u16* __restrict__ W2, int tile0, f32x4* acc,
    int c, int g, int lane, int w, u16* __restrict__ panel)
{
  const u16* a = A + c*lda + g*8;
  {   // prologue: stage chunk 0 -> buf0
    short8 ld[NT];
    #pragma unroll
    for (int jj = 0; jj < NT; ++jj)
      ld[jj] = *(const short8*)(W2 + ((size_t)(tile0 + w + 8*jj)*NKC)*512 + (size_t)lane*8);
    #pragma unroll
    for (int jj = 0; jj < NT; ++jj)
      *(short8*)(panel + (w + 8*jj)*512 + lane*8) = ld[jj];
  }
  __syncthreads();
  #pragma unroll 2
  for (int kk = 0; kk < NKC; ++kk){
    u16* cur = panel + (kk & 1)*PANEL;
    u16* nxt = panel + ((kk & 1) ^ 1)*PANEL;
    short8 ld[NT];
    if (kk + 1 < NKC){
      #pragma unroll
      for (int jj = 0; jj < NT; ++jj)
        ld[jj] = *(const short8*)(W2 + ((size_t)(tile0 + w + 8*jj)*NKC + kk + 1)*512 + (size_t)lane*8);
    }
    short8 av = *(const short8*)(a + 32*kk);
    #pragma unroll
    for (int jj = 0; jj < NT; ++jj){
      short8 bv = *(const short8*)(cur + (w + 8*jj)*512 + lane*8);
      acc[jj] = __builtin_amdgcn_mfma_f32_16x16x32_bf16(av, bv, acc[jj], 0, 0, 0);
    }
    if (kk + 1 < NKC){
      #pragma unroll
      for (int jj = 0; jj < NT; ++jj)
        *(short8*)(nxt + (w + 8*jj)*512 + lane*8) = ld[jj];
    }
    __syncthreads();
  }
}

__global__ __launch_bounds__(NTH, 1) void nnfo_main(Params pr)
{
  __shared__ Smem sm;
  const int tid  = threadIdx.x;
  const int lane = tid & 63;
  const int w    = tid >> 6;          // wave 0..7
  const int c = lane & 15;            // output col / A row
  const int g = lane >> 4;            // k-group; output rows g*4+i
  const int wg = blockIdx.x;
  const int row0 = wg * 16;
  u16* panel = &sm.panel[0][0];

  float loss = 0.0f;
  float hreg[6][4];      // owner h: thread (w,c,g) owns h[g*4+i][(w+8j)*16+c]
  float zreg[6][4];

  // ---- prologue: rc = relu(cov@Wc1^T + bc1) -> p_f ----
  for (int it = tid; it < 16*COVH; it += NTH){
    int r = it >> 7, j = it & 127;
    float acc = pr.bc1[j];
    const float* cv = pr.cov + (size_t)(row0 + r)*COVSZ;
    const float* wv = pr.Wc1 + (size_t)j*COVSZ;
    for (int k = 0; k < COVSZ; ++k) acc += cv[k]*wv[k];
    sm.p_f[r*LPF + j] = fmaxf(acc, 0.0f);
  }
  __syncthreads();
  // ---- h0 = tanh(rc@Wc2^T + bc2) at owner threads (ref k-order) ----
  #pragma unroll
  for (int j = 0; j < 6; ++j){
    int n = (w + 8*j)*16 + c;
    const float* wv = pr.Wc2 + (size_t)n*COVH;
    #pragma unroll
    for (int i = 0; i < 4; ++i){
      int r = g*4 + i;
      float acc = pr.bc2[n];
      for (int k = 0; k < COVH; ++k) acc += sm.p_f[r*LPF + k]*wv[k];
      float h = tanh_f(acc);
      hreg[j][i] = h;
      sm.h_b[r*LHB + n] = f2bf(h);
    }
  }
  __syncthreads();

  // pm1: ph1 = relu(h@Wp1^T + bp1)   (32 tiles, NT=4)
  auto pm1 = [&]() {
    f32x4 acc[4] = {};
    panelGemm<24, 4>(sm.h_b, LHB, pr.Wp1, 0, acc, c, g, lane, w, panel);
    #pragma unroll
    for (int j = 0; j < 4; ++j){
      int n = (w + 8*j)*16 + c;
      float b = pr.bp1[n];
      #pragma unroll
      for (int i = 0; i < 4; ++i)
        sm.u.ph1[(g*4 + i)*LPH + n] = f2bf(fmaxf(acc[j][i] + b, 0.0f));
    }
  };
  // pm2: p = ph1@Wp2^T + bp2  (8 tiles, NT=1)
  auto pm2 = [&](bool write_pb) {
    f32x4 acc[1] = {};
    panelGemm<16, 1>(sm.u.ph1, LPH, pr.Wp2, 0, acc, c, g, lane, w, panel);
    int n = w*16 + c;
    float b = pr.bp2[n];
    #pragma unroll
    for (int i = 0; i < 4; ++i){
      float v = acc[0][i] + b;
      sm.p_f[(g*4 + i)*LPF + n] = v;
      if (write_pb) sm.p_b[(g*4 + i)*LPB + n] = f2bf(v);
    }
  };

  // initial p = p_model(h0)
  pm1();
  __syncthreads();
  pm2(true);
  __syncthreads();

  float Xs[2], Ms[2];

  #pragma unroll 1
  for (int t = 0; t < NUM_T; ++t){
    if (tid < 16) sm.om[t & 1][tid] = pr.obs[(size_t)t*BATCH + row0 + tid];

    // ---- A1: z = sigmoid(p@Wxz + bxz + h@Whz); accn = p@Wxn (partial) ----
    {
      f32x4 accz[6] = {}, accn[6] = {};
      panelGemm<4, 6>(sm.p_b, LPB, pr.Wxz, 0, accz, c, g, lane, w, panel);
      panelGemm<24, 6>(sm.h_b, LHB, pr.Whz, 0, accz, c, g, lane, w, panel);
      panelGemm<4, 6>(sm.p_b, LPB, pr.Wxn, 0, accn, c, g, lane, w, panel);
      #pragma unroll
      for (int j = 0; j < 6; ++j){
        int n = (w + 8*j)*16 + c;
        float b = pr.bxz[n];
        #pragma unroll
        for (int i = 0; i < 4; ++i){
          int r = g*4 + i;
          float z = sigm(accz[j][i] + b);
          sm.u.zh[r*LZH + n] = f2bf(z*hreg[j][i]);  // fp32 z * fp32 h -> bf16
          zreg[j][i] = bf2f(f2bf(z));               // bf16 round-trip (= r1 path)
        }
      }
      __syncthreads();

      // ---- A2: n = tanh(accn + bxn + (z*h)@Whn); h += dt*(1-z)*(n-h) ----
      panelGemm<24, 6>(sm.u.zh, LZH, pr.Whn, 0, accn, c, g, lane, w, panel);
      #pragma unroll
      for (int j = 0; j < 6; ++j){
        int n = (w + 8*j)*16 + c;
        float b = pr.bxn[n];
        #pragma unroll
        for (int i = 0; i < 4; ++i){
          int r = g*4 + i;
          float nv = tanh_f(accn[j][i] + b);
          float z  = zreg[j][i];
          float h  = hreg[j][i];
          h = h + DT_*(1.0f - z)*(nv - h);
          hreg[j][i] = h;
          sm.h_b[r*LHB + n] = f2bf(h);
        }
      }
    }
    __syncthreads();

    // ---- B,C: p2 = p_model(h_ode) -> fp32 only ----
    pm1();
    __syncthreads();
    pm2(false);
    __syncthreads();

    // ---- D: nll_pre + build gi (stash X, M*om) ----
    #pragma unroll
    for (int q = 0; q < 2; ++q){
      int it = tid + q*NTH;
      int r = it >> 6, d = it & 63;
      size_t xoff = ((size_t)t*BATCH + row0 + r)*DIM + d;
      float Xv = pr.X[xoff];
      float om = sm.om[t & 1][r] ? 1.0f : 0.0f;
      float Mv = pr.M[xoff] * om;
      Xs[q] = Xv; Ms[q] = Mv;
      float mean = sm.p_f[r*LPF + d];
      float var  = sm.p_f[r*LPF + 64 + d];
      float av   = fabsf(var) + VEPS;
      float inv  = rsqrtf(av);
      float errv = (Xv - mean)*inv;
      loss += 0.5f*(errv*errv + __logf(av))*Mv;
      #pragma unroll
      for (int p = 0; p < PREP; ++p){
        float s = pr.bprep[d*PREP + p]
                + Xv  * pr.wprep[(d*4 + 0)*PREP + p]
                + mean* pr.wprep[(d*4 + 1)*PREP + p]
                + av  * pr.wprep[(d*4 + 2)*PREP + p]
                + errv* pr.wprep[(d*4 + 3)*PREP + p];
        sm.u.gi[r*LGI + d*PREP + p] = f2bf(fmaxf(s, 0.0f)*Mv);
      }
    }
    __syncthreads();

    // ---- E: GRUCell jump (6 gate passes; per-acc k-order = r8 = bit-exact) ----
    {
      float rr[6][4], zz[6][4], hn_buf[6][4];
      {
        f32x4 t1[6] = {}, t2[6] = {};
        panelGemm<20, 6>(sm.u.gi, LGI, pr.Wih, 0,  t1, c, g, lane, w, panel);
        panelGemm<24, 6>(sm.h_b,  LHB, pr.Whh, 0,  t2, c, g, lane, w, panel);
        #pragma unroll
        for (int j = 0; j < 6; ++j){
          int n = (w + 8*j)*16 + c;
          float bi = pr.bih[n], bh = pr.bhh[n];
          #pragma unroll
          for (int i = 0; i < 4; ++i)
            rr[j][i] = sigm((t1[j][i] + bi) + (t2[j][i] + bh));
        }
      }
      {
        f32x4 t1[6] = {}, t2[6] = {};
        panelGemm<20, 6>(sm.u.gi, LGI, pr.Wih, 48, t1, c, g, lane, w, panel);
        panelGemm<24, 6>(sm.h_b,  LHB, pr.Whh, 48, t2, c, g, lane, w, panel);
        #pragma unroll
        for (int j = 0; j < 6; ++j){
          int n = (w + 8*j)*16 + c;
          float bi = pr.bih[HID + n], bh = pr.bhh[HID + n];
          #pragma unroll
          for (int i = 0; i < 4; ++i)
            zz[j][i] = sigm((t1[j][i] + bi) + (t2[j][i] + bh));
        }
      }
      {
        f32x4 t1[6] = {}, t2[6] = {};
        panelGemm<20, 6>(sm.u.gi, LGI, pr.Wih, 96, t1, c, g, lane, w, panel);
        panelGemm<24, 6>(sm.h_b,  LHB, pr.Whh, 96, t2, c, g, lane, w, panel);
        #pragma unroll
        for (int j = 0; j < 6; ++j){
          int n = (w + 8*j)*16 + c;
          float bi = pr.bih[2*HID + n], bh = pr.bhh[2*HID + n];
          #pragma unroll
          for (int i = 0; i < 4; ++i){
            float nn = tanh_f((t1[j][i] + bi) + rr[j][i]*(t2[j][i] + bh));
            hn_buf[j][i] = (1.0f - zz[j][i])*nn + zz[j][i]*hreg[j][i];
          }
        }
      }
      // last panelGemm ended with a barrier => all h_b reads complete
      #pragma unroll
      for (int j = 0; j < 6; ++j){
        int n = (w + 8*j)*16 + c;
        #pragma unroll
        for (int i = 0; i < 4; ++i){
          int r = g*4 + i;
          if (sm.om[t & 1][r]){
            float v = hn_buf[j][i];
            hreg[j][i] = v;
            sm.h_b[r*LHB + n] = f2bf(v);
          }
        }
      }
    }
    __syncthreads();

    // ---- F,G: p3 = p_model(h_jump) -> fp32 + bf16 (next step's pre-ODE p) ----
    pm1();
    __syncthreads();
    pm2(true);
    __syncthreads();

    // ---- H: nll_post (stashed X, M*om) ----
    #pragma unroll
    for (int q = 0; q < 2; ++q){
      int it = tid + q*NTH;
      int r = it >> 6, d = it & 63;
      float mean = sm.p_f[r*LPF + d];
      float var  = sm.p_f[r*LPF + 64 + d];
      float av   = fabsf(var) + VEPS;
      float inv  = rsqrtf(av);
      float errv = (Xs[q] - mean)*inv;
      loss += 0.5f*(errv*errv + __logf(av))*Ms[q];   // MIXING = 1
    }
  }

  __syncthreads();
  // ---- write h rows (fp32) from owner registers ----
  #pragma unroll
  for (int j = 0; j < 6; ++j){
    int n = (w + 8*j)*16 + c;
    #pragma unroll
    for (int i = 0; i < 4; ++i){
      int r = g*4 + i;
      pr.out_h[(size_t)(row0 + r)*HID + n] = hreg[j][i];
    }
  }
  // ---- loss reduce ----
  #pragma unroll
  for (int off = 32; off >= 1; off >>= 1) loss += __shfl_down(loss, off);
  if (lane == 0) sm.red[w] = loss;
  __syncthreads();
  if (tid == 0){
    float s = 0.0f;
    for (int i = 0; i < NWAVE; ++i) s += sm.red[i];
    pr.partials[wg] = s;
  }
}

// Convert + swizzle W (N x K, f32 row-major) -> fragment-major bf16:
// dst[((t*ks + k)*64 + lane)*8 + e] = W[t*16 + (lane&15)][k*32 + (lane>>4)*8 + e]
__global__ void k_swz(const float* __restrict__ s, u16* __restrict__ d, int N, int K){
  int i = blockIdx.x*blockDim.x + threadIdx.x;
  if (i >= N*K) return;
  int e    = i & 7;
  int lane = (i >> 3) & 63;
  int rest = i >> 9;             // t*ks + k
  int ks = K >> 5;
  int k = rest % ks, t = rest / ks;
  int cc = lane & 15, gg = lane >> 4;
  d[i] = f2bf(s[(size_t)(t*16 + cc)*K + (k*32 + gg*8 + e)]);
}

__global__ void k_final(const float* __restrict__ partials, float* __restrict__ out_loss){
  float v = partials[threadIdx.x];
  #pragma unroll
  for (int off = 32; off >= 1; off >>= 1) v += __shfl_down(v, off);
  if (threadIdx.x == 0) out_loss[0] = v;
}

extern "C" void kernel_launch(void* const* d_in, const int* in_sizes, int n_in,
                              void* d_out, int out_size, void* d_ws, size_t ws_size,
                              hipStream_t stream)
{
  const float* X   = (const float*)d_in[0];
  const float* M   = (const float*)d_in[1];
  const int*   obs = (const int*)  d_in[2];
  const float* cov = (const float*)d_in[3];
  const float* Wxz = (const float*)d_in[4];
  const float* bxz = (const float*)d_in[5];
  const float* Wxn = (const float*)d_in[6];
  const float* bxn = (const float*)d_in[7];
  const float* Whz = (const float*)d_in[8];
  const float* Whn = (const float*)d_in[9];
  const float* Wp1 = (const float*)d_in[10];
  const float* bp1 = (const float*)d_in[11];
  const float* Wp2 = (const float*)d_in[12];
  const float* bp2 = (const float*)d_in[13];
  const float* Wc1 = (const float*)d_in[14];
  const float* bc1 = (const float*)d_in[15];
  const float* Wc2 = (const float*)d_in[16];
  const float* bc2 = (const float*)d_in[17];
  const float* Wih = (const float*)d_in[18];
  const float* Whh = (const float*)d_in[19];
  const float* bih = (const float*)d_in[20];
  const float* bhh = (const float*)d_in[21];
  const float* wprep = (const float*)d_in[22];
  const float* bprep = (const float*)d_in[23];

  u16* w = (u16*)d_ws;
  u16* wXZ = w + 0;         // 768*128
  u16* wXN = w + 98304;     // 768*128
  u16* wHZ = w + 196608;    // 768*768
  u16* wHN = w + 786432;    // 768*768
  u16* wP1 = w + 1376256;   // 512*768
  u16* wP2 = w + 1769472;   // 128*512
  u16* wIH = w + 1835008;   // 2304*640
  u16* wHH = w + 3309568;   // 2304*768
  float* partials = (float*)((char*)d_ws + 10158080);

  struct CV { const float* s; u16* d; int N; int K; } cvs[8] = {
    {Wxz, wXZ, 768, 128}, {Wxn, wXN, 768, 128}, {Whz, wHZ, 768, 768}, {Whn, wHN, 768, 768},
    {Wp1, wP1, 512, 768}, {Wp2, wP2, 128, 512}, {Wih, wIH, 2304, 640}, {Whh, wHH, 2304, 768},
  };
  for (int i = 0; i < 8; ++i){
    int n = cvs[i].N * cvs[i].K;
    k_swz<<<(n + 255)/256, 256, 0, stream>>>(cvs[i].s, cvs[i].d, cvs[i].N, cvs[i].K);
  }

  Params pr { X, M, obs, cov, bxz, bxn, bp1, bp2, bc1, bc2, bih, bhh, wprep, bprep,
              Wc1, Wc2, wXZ, wXN, wHZ, wHN, wP1, wP2, wIH, wHH,
              (float*)d_out, partials };
  nnfo_main<<<NWG, NTH, 0, stream>>>(pr);
  k_final<<<1, 64, 0, stream>>>(partials, (float*)d_out + (size_t)BATCH*HID);
}